// Round 11
// baseline (402.809 us; speedup 1.0000x reference)
//
#include <hip/hip_runtime.h>

#define N_NODES 100000
#define N_EDGES 1600000
#define N_GRAPHS 512
#define HID 64
#define NUM_CLASSES 100
#define ID_OFFSET 1500
#define BN_EPS 1e-5f
#define CAP 64
#define NBKT 256
#define BSHIFT 9
#define NUSED ((N_NODES + 511) >> 9)
#define CBLK 98
#define CHUNK 16384

typedef __attribute__((ext_vector_type(8))) short short8;
typedef __attribute__((ext_vector_type(4))) float floatx4;

__device__ __forceinline__ float b2f(unsigned short u) {
    return __builtin_bit_cast(float, ((unsigned)u) << 16);
}
__device__ __forceinline__ unsigned short f2b(float f) {   // RNE
    unsigned x = __builtin_bit_cast(unsigned, f);
    x += 0x7FFFu + ((x >> 16) & 1u);
    return (unsigned short)(x >> 16);
}

// swizzled granule layout: 16-row tiles, 8 granules(16B)/row, granule slot = (row&15)^q
#define XSH(row, qq) ((((((row) >> 4) << 7) + ((qq) << 4) + (((row) & 15) ^ (qq))) * 8))

// ---------------- binned CSR build (unchanged since R5) ----------------

__global__ __launch_bounds__(1024) void bhist_kernel(const int* __restrict__ dst,
                                                     int* __restrict__ btot) {
    __shared__ int hist[NBKT];
    int t = threadIdx.x;
    if (t < NBKT) hist[t] = 0;
    __syncthreads();
    int base = blockIdx.x * CHUNK;
    for (int k = 0; k < 16; ++k) {
        int i = base + k * 1024 + t;
        if (i < N_EDGES) {
            int d = dst[i];
            if (d >= 0) atomicAdd(&hist[((unsigned)d >> BSHIFT) & (NBKT - 1)], 1);
        }
    }
    __syncthreads();
    if (t < NBKT && hist[t] > 0) atomicAdd(&btot[t], hist[t]);
}

__global__ void bscan_kernel(const int* __restrict__ btot, int* __restrict__ bstart,
                             int* __restrict__ cursor) {
    __shared__ int tmp[NBKT];
    int t = threadIdx.x;
    int v = btot[t];
    tmp[t] = v;
    __syncthreads();
    for (int off = 1; off < NBKT; off <<= 1) {
        int add = (t >= off) ? tmp[t - off] : 0;
        __syncthreads();
        tmp[t] += add;
        __syncthreads();
    }
    int excl = tmp[t] - v;
    bstart[t] = excl;
    cursor[t] = excl;
    if (t == NBKT - 1) bstart[NBKT] = tmp[t];
}

__global__ __launch_bounds__(1024) void bin_kernel(const int* __restrict__ src,
                                                   const int* __restrict__ dst,
                                                   int* __restrict__ cursor,
                                                   int* __restrict__ rec) {
    __shared__ int hist[NBKT];
    __shared__ int base_s[NBKT];
    int t = threadIdx.x;
    if (t < NBKT) hist[t] = 0;
    __syncthreads();
    int cb = blockIdx.x * CHUNK;
    int d_[16], s_[16];
#pragma unroll
    for (int k = 0; k < 16; ++k) {
        int i = cb + k * 1024 + t;
        d_[k] = (i < N_EDGES) ? dst[i] : -1;
        s_[k] = (i < N_EDGES) ? src[i] : 0;
        if (d_[k] >= 0) atomicAdd(&hist[((unsigned)d_[k] >> BSHIFT) & (NBKT - 1)], 1);
    }
    __syncthreads();
    if (t < NBKT) base_s[t] = (hist[t] > 0) ? atomicAdd(&cursor[t], hist[t]) : 0;
    __syncthreads();
    if (t < NBKT) hist[t] = 0;
    __syncthreads();
#pragma unroll
    for (int k = 0; k < 16; ++k) {
        if (d_[k] >= 0) {
            unsigned d = (unsigned)d_[k];
            int b = (d >> BSHIFT) & (NBKT - 1);
            int p = atomicAdd(&hist[b], 1);
            int g = base_s[b] + p;
            if ((unsigned)g < N_EDGES)
                rec[g] = ((int)(d & 511) << 17) | (s_[k] & 0x1FFFF);
        }
    }
}

__global__ __launch_bounds__(1024) void fill_kernel(const int* __restrict__ rec,
                                                    const int* __restrict__ bstart,
                                                    int* __restrict__ cnt,
                                                    int* __restrict__ srcs) {
    __shared__ int lcnt[512];
    int t = threadIdx.x;
    int b = blockIdx.x;
    if (t < 512) lcnt[t] = 0;
    __syncthreads();
    int s0 = bstart[b], s1 = bstart[b + 1];
    if (s0 < 0) s0 = 0;
    if (s1 > N_EDGES) s1 = N_EDGES;
    for (int i = s0 + t; i < s1; i += 1024) {
        unsigned r = (unsigned)rec[i];
        int dl = (int)((r >> 17) & 511);
        int s = (int)(r & 0x1FFFF);
        int node = (b << BSHIFT) + dl;
        int p = atomicAdd(&lcnt[dl], 1);
        if (p < CAP && node < N_NODES) srcs[(node << 6) + p] = s;
    }
    __syncthreads();
    if (t < 512) {
        int node = (b << BSHIFT) + t;
        if (node < N_NODES) cnt[node] = lcnt[t];
    }
}

// ---------------- W pre-convert + pre-swizzle, hi/lo split ----------------

__global__ void wprep_kernel(const float* __restrict__ Ws, unsigned short* __restrict__ whi,
                             unsigned short* __restrict__ wlo) {
    int G = blockIdx.x * blockDim.x + threadIdx.x;   // granule id, 3*1536
    if (G >= 3 * 1536) return;
    int l = G / 1536, Gp = G % 1536;
    int mm = Gp >> 9, rem = Gp & 511;
    int kq = rem >> 6, n = rem & 63;
    const float* Wp = Ws + l * 12288 + mm * 4096 + (kq * 8) * 64 + n;
    unsigned short uh[8], ul[8];
#pragma unroll
    for (int j = 0; j < 8; ++j) {
        float w = Wp[j * 64];
        unsigned short hi = f2b(w);
        uh[j] = hi;
        ul[j] = f2b(w - b2f(hi));
    }
    size_t off = (size_t)l * 12288 + (mm << 12) + XSH(n, kq);
    *(short8*)&whi[off] = *(short8*)uh;
    *(short8*)&wlo[off] = *(short8*)ul;
}

// ---------------- embedding gather -> bf16 h, fused graph-span detection ----------------

__global__ void embed_kernel(const int* __restrict__ node_ids, const int* __restrict__ gid,
                             const float* __restrict__ emb, unsigned short* __restrict__ h,
                             int* __restrict__ gs, int* __restrict__ ge) {
    int idx = blockIdx.x * blockDim.x + threadIdx.x;
    if (idx < N_NODES * 32) {
        int n = idx >> 5, cp = idx & 31;
        const float2 e = *(const float2*)(emb + (((size_t)(node_ids[n] + ID_OFFSET)) << 6) + cp * 2);
        unsigned v = (unsigned)f2b(e.x) | ((unsigned)f2b(e.y) << 16);
        ((unsigned*)h)[n * 32 + cp] = v;
        if (cp == 0) {   // sorted graph_ids -> span boundaries, no atomics
            int g = gid[n] & (N_GRAPHS - 1);
            if (n == 0 || (gid[n - 1] & (N_GRAPHS - 1)) != g) gs[g] = n;
            if (n == N_NODES - 1 || (gid[n + 1] & (N_GRAPHS - 1)) != g) ge[g] = n + 1;
        }
    }
}

// ---------------- GIN aggregation (R10 half-wave u32 version, unchanged) ----------------

__global__ __launch_bounds__(256) void agg_kernel(const unsigned short* __restrict__ x,
                                                  const int* __restrict__ cnt,
                                                  const int* __restrict__ srcs,
                                                  const float* __restrict__ eps, int l,
                                                  const float* __restrict__ stats,
                                                  const float* __restrict__ gamma,
                                                  const float* __restrict__ beta,
                                                  unsigned short* __restrict__ out) {
    int node = __builtin_amdgcn_readfirstlane((blockIdx.x << 2) + (threadIdx.x >> 6));
    if (node >= N_NODES) return;
    int lane = threadIdx.x & 63;
    int half = lane >> 5;
    int cl = lane & 31;                    // u32 column: channels 2cl, 2cl+1
    const unsigned* __restrict__ xu = (const unsigned*)x;
    int deg = cnt[node];
    int degc = deg < 0 ? 0 : (deg > CAP ? CAP : deg);
    const int* __restrict__ row = srcs + ((size_t)node << 6);
    float scale = 1.0f + eps[l];

    float A0[4] = {0.f, 0.f, 0.f, 0.f};
    float A1[4] = {0.f, 0.f, 0.f, 0.f};
    {
        unsigned u = xu[(size_t)node * 32 + cl];
        if (half == 0) {
            A0[0] = scale * b2f((unsigned short)(u & 0xFFFF));
            A1[0] = scale * b2f((unsigned short)(u >> 16));
        }
    }
    int j = 0;
    for (; j + 16 <= degc; j += 16) {
        unsigned uv[8];
#pragma unroll
        for (int k = 0; k < 8; ++k) {
            int ia = row[j + 2 * k] & 0x1FFFF;
            int ib = row[j + 2 * k + 1] & 0x1FFFF;
            int idx = half ? ib : ia;
            uv[k] = xu[(size_t)idx * 32 + cl];
        }
#pragma unroll
        for (int k = 0; k < 8; ++k) {
            A0[k & 3] += b2f((unsigned short)(uv[k] & 0xFFFF));
            A1[k & 3] += b2f((unsigned short)(uv[k] >> 16));
        }
    }
    for (; j + 8 <= degc; j += 8) {
        unsigned uv[4];
#pragma unroll
        for (int k = 0; k < 4; ++k) {
            int ia = row[j + 2 * k] & 0x1FFFF;
            int ib = row[j + 2 * k + 1] & 0x1FFFF;
            int idx = half ? ib : ia;
            uv[k] = xu[(size_t)idx * 32 + cl];
        }
#pragma unroll
        for (int k = 0; k < 4; ++k) {
            A0[k] += b2f((unsigned short)(uv[k] & 0xFFFF));
            A1[k] += b2f((unsigned short)(uv[k] >> 16));
        }
    }
    for (; j + 2 <= degc; j += 2) {
        int ia = row[j] & 0x1FFFF, ib = row[j + 1] & 0x1FFFF;
        int idx = half ? ib : ia;
        unsigned u = xu[(size_t)idx * 32 + cl];
        A0[1] += b2f((unsigned short)(u & 0xFFFF));
        A1[1] += b2f((unsigned short)(u >> 16));
    }
    if (j < degc && half == 0) {
        unsigned u = xu[(size_t)(row[j] & 0x1FFFF) * 32 + cl];
        A0[2] += b2f((unsigned short)(u & 0xFFFF));
        A1[2] += b2f((unsigned short)(u >> 16));
    }
    float S0 = (A0[0] + A0[1]) + (A0[2] + A0[3]);
    float S1 = (A1[0] + A1[1]) + (A1[2] + A1[3]);
    S0 += __shfl_xor(S0, 32);
    S1 += __shfl_xor(S1, 32);

    if (half == 0) {
        float a0f = 1.0f, a1f = 1.0f, b0f = 0.0f, b1f = 0.0f;
        if (l > 0) {
            int lp = l - 1;
            int c0 = 2 * cl, c1 = 2 * cl + 1;
            float mean0 = stats[lp * 128 + c0] * (1.0f / N_NODES);
            float var0 = stats[lp * 128 + 64 + c0] * (1.0f / N_NODES) - mean0 * mean0;
            float r0 = rsqrtf(var0 + BN_EPS);
            a0f = gamma[lp * 64 + c0] * r0;
            b0f = beta[lp * 64 + c0] - mean0 * a0f;
            float mean1 = stats[lp * 128 + c1] * (1.0f / N_NODES);
            float var1 = stats[lp * 128 + 64 + c1] * (1.0f / N_NODES) - mean1 * mean1;
            float r1 = rsqrtf(var1 + BN_EPS);
            a1f = gamma[lp * 64 + c1] * r1;
            b1f = beta[lp * 64 + c1] - mean1 * a1f;
        }
        float v0 = fmaf(a0f, S0, (scale + (float)degc) * b0f);
        float v1 = fmaf(a1f, S1, (scale + (float)degc) * b1f);
        ((unsigned*)out)[(size_t)node * 32 + cl] =
            (unsigned)f2b(v0) | ((unsigned)f2b(v1) << 16);
    }
}

// ---------------- MFMA MLP v3: Whi in LDS (R9 path restored), Wlo from global ----------------
// R10 regression post-mortem: Whi-from-global put ~200-500cyc L2 latency in the MFMA
// dependency chain while grid(782)/CU kept occupancy at 3 blocks/CU regardless of LDS.
// Whi LDS copy is a pure int4 copy of the pre-swizzled image (no conflicts, no repack).

__global__ __launch_bounds__(256) void mlp_kernel(unsigned short* __restrict__ x,
                                                  const unsigned short* __restrict__ whi,
                                                  const unsigned short* __restrict__ wlo,
                                                  const float* __restrict__ bs, int l,
                                                  float* __restrict__ stats,
                                                  const int* __restrict__ graph_ids,
                                                  float* __restrict__ pooled, int last) {
    __shared__ __align__(16) unsigned short xs[128 * 64];    // 16 KB
    __shared__ __align__(16) unsigned short wt[3 * 64 * 64]; // 24 KB (Whi)
    __shared__ int garr[128];
    __shared__ float ssum[256], sqq[256];
    int t = threadIdx.x;
    int nodebase = blockIdx.x * 128;
    int lane = t & 63, w = t >> 6;

    // wave-local garr + x staging
    if (lane < 32) {
        int n = nodebase + w * 32 + lane;
        garr[w * 32 + lane] = (n < N_NODES) ? (graph_ids[n] & (N_GRAPHS - 1)) : -1;
    }
#pragma unroll
    for (int i = 0; i < 4; ++i) {
        int g = i * 64 + lane;
        int rl = g >> 3, qr = g & 7;
        int row = w * 32 + rl;
        const int4 v = *(const int4*)(x + (((size_t)(nodebase + row)) << 6) + qr * 8);
        *(int4*)&xs[XSH(row, qr)] = v;
    }
    // stage Whi: pure int4 copy of the pre-swizzled image (cooperative)
    {
        const unsigned short* wsrc = whi + (size_t)l * 12288;
#pragma unroll
        for (int i = 0; i < 6; ++i) {
            int g = i * 256 + t;
            *(int4*)&wt[g * 8] = *(const int4*)&wsrc[g * 8];
        }
    }
    __syncthreads();

    int m = lane & 15, q = lane >> 4;
    const float* bb = bs + l * 3 * 64;
    const unsigned short* wlol = wlo + (size_t)l * 12288;
    for (int mm = 0; mm < 3; ++mm) {
        floatx4 acc[2][4];
#pragma unroll
        for (int tj = 0; tj < 4; ++tj) {
            float bv = bb[mm * 64 + tj * 16 + m];
#pragma unroll
            for (int ti = 0; ti < 2; ++ti) acc[ti][tj] = (floatx4){bv, bv, bv, bv};
        }
#pragma unroll
        for (int kc = 0; kc < 2; ++kc) {
            short8 a[2], bh[4], bl[4];
#pragma unroll
            for (int ti = 0; ti < 2; ++ti)
                a[ti] = *(const short8*)&xs[XSH(w * 32 + ti * 16 + m, kc * 4 + q)];
#pragma unroll
            for (int tj = 0; tj < 4; ++tj) {
                bh[tj] = *(const short8*)&wt[(mm << 12) + XSH(tj * 16 + m, kc * 4 + q)];
                bl[tj] = *(const short8*)&wlol[(mm << 12) + XSH(tj * 16 + m, kc * 4 + q)];
            }
#pragma unroll
            for (int ti = 0; ti < 2; ++ti)
#pragma unroll
                for (int tj = 0; tj < 4; ++tj) {
                    acc[ti][tj] = __builtin_amdgcn_mfma_f32_16x16x32_bf16(a[ti], bh[tj], acc[ti][tj], 0, 0, 0);
                    acc[ti][tj] = __builtin_amdgcn_mfma_f32_16x16x32_bf16(a[ti], bl[tj], acc[ti][tj], 0, 0, 0);
                }
        }
#pragma unroll
        for (int ti = 0; ti < 2; ++ti)
#pragma unroll
            for (int tj = 0; tj < 4; ++tj) {
                int col = tj * 16 + m;
#pragma unroll
                for (int r = 0; r < 4; ++r) {
                    int row = w * 32 + ti * 16 + q * 4 + r;
                    float v = acc[ti][tj][r];
                    xs[XSH(row, col >> 3) + (col & 7)] = f2b(v > 0.f ? v : 0.f);
                }
            }
    }

    // epilogue: store-back (skipped on last layer), stats + segmented pooling
    if (!last) {
        unsigned* xo = (unsigned*)x;
#pragma unroll
        for (int it = 0; it < 16; ++it) {
            int row = w * 32 + (lane >> 5) + it * 2;
            int cp = lane & 31;
            int col = cp * 2;
            unsigned val = *(const unsigned*)&xs[XSH(row, col >> 3) + (col & 7)];
            int node = nodebase + row;
            if (node < N_NODES) xo[(size_t)node * 32 + cp] = val;
        }
    }
    {
        int c = lane;
        float s = 0.f, q2 = 0.f, acc2 = 0.f;
        int cur = -1;
        for (int k = 0; k < 32; ++k) {
            int row = w * 32 + k;
            int g = garr[row];                 // wave-uniform, wave-local
            if (g >= 0) {
                float v = b2f(xs[XSH(row, c >> 3) + (c & 7)]);
                s += v;
                q2 += v * v;
                if (g != cur) {
                    if (cur >= 0) atomicAdd(&pooled[cur * 192 + l * 64 + c], acc2);
                    acc2 = 0.f;
                    cur = g;
                }
                acc2 += v;
            }
        }
        if (cur >= 0) atomicAdd(&pooled[cur * 192 + l * 64 + c], acc2);
        ssum[t] = s;
        sqq[t] = q2;
    }
    __syncthreads();
    if (t < 64) {
        float S = ssum[t] + ssum[t + 64] + ssum[t + 128] + ssum[t + 192];
        float Q = sqq[t] + sqq[t + 64] + sqq[t + 128] + sqq[t + 192];
        atomicAdd(&stats[l * 128 + t], S);
        atomicAdd(&stats[l * 128 + 64 + t], Q);
    }
}

// ---------------- final classifier: (a,b) from stats inline; gf = a*pool + b*count ----------------

__global__ __launch_bounds__(256) void out_kernel(const float* __restrict__ pooled,
                                                  const float* __restrict__ stats,
                                                  const float* __restrict__ gamma,
                                                  const float* __restrict__ beta,
                                                  const int* __restrict__ gs,
                                                  const int* __restrict__ ge,
                                                  const float* __restrict__ Wo,
                                                  const float* __restrict__ bo,
                                                  float* __restrict__ out) {
    __shared__ float sab[384];   // [l][0:64]=a, [l][64:128]=b
    int t = threadIdx.x;
    if (t < 192) {
        int l2 = t / 64, c = t & 63;
        float mean = stats[l2 * 128 + c] * (1.0f / N_NODES);
        float var = stats[l2 * 128 + 64 + c] * (1.0f / N_NODES) - mean * mean;
        float rstd = rsqrtf(var + BN_EPS);
        float a = gamma[l2 * 64 + c] * rstd;
        sab[l2 * 128 + c] = a;
        sab[l2 * 128 + 64 + c] = beta[l2 * 64 + c] - mean * a;
    }
    __syncthreads();
    int idx = blockIdx.x * blockDim.x + t;
    if (idx < N_GRAPHS * NUM_CLASSES) {
        int g = idx / NUM_CLASSES, k = idx % NUM_CLASSES;
        float cg = (float)(ge[g] - gs[g]);
        float acc = bo[k];
        for (int l2 = 0; l2 < 3; ++l2)
            for (int c = 0; c < 64; ++c) {
                float gf = fmaf(sab[l2 * 128 + c], pooled[g * 192 + l2 * 64 + c],
                                sab[l2 * 128 + 64 + c] * cg);
                acc = fmaf(gf, Wo[(l2 * 64 + c) * NUM_CLASSES + k], acc);
            }
        out[idx] = acc;
    }
}

extern "C" void kernel_launch(void* const* d_in, const int* in_sizes, int n_in,
                              void* d_out, int out_size, void* d_ws, size_t ws_size,
                              hipStream_t stream) {
    const int*   node_ids  = (const int*)d_in[0];
    const int*   edge_src  = (const int*)d_in[1];
    const int*   edge_dst  = (const int*)d_in[2];
    const int*   graph_ids = (const int*)d_in[3];
    const float* emb       = (const float*)d_in[4];
    const float* Ws        = (const float*)d_in[5];
    const float* bs        = (const float*)d_in[6];
    const float* gamma     = (const float*)d_in[7];
    const float* beta      = (const float*)d_in[8];
    const float* eps       = (const float*)d_in[9];
    const float* W_out     = (const float*)d_in[10];
    const float* b_out     = (const float*)d_in[11];
    float* out = (float*)d_out;

    // workspace: h/xin bf16 with 128-row slack for last-tile over-reads
    unsigned short* h    = (unsigned short*)d_ws;         // 6,400,000 sh (+8192 slack)
    unsigned short* xin  = h + 6400000 + 8192;            // 6,400,000 sh (+8192 slack)
    unsigned short* whi  = xin + 6400000 + 8192;          // 36,864 sh (pre-swizzled W hi)
    unsigned short* wlo  = whi + 36864;                   // 36,864 sh (pre-swizzled W lo)
    int*   srcs   = (int*)(wlo + 36864);                  // 6,400,000 i
    int*   rec    = srcs + 6400000;                       // 1,600,000 i
    float* pooled = (float*)(rec + 1600000);              // 98,304 f
    float* stats  = pooled + 98304;                       // 384 f (3 layer slots)
    int*   cnt    = (int*)(stats + 384);                  // 100,000 i
    int*   gs     = cnt + 100000;                         // 512 i
    int*   ge     = gs + 512;                             // 512 i
    int*   btot   = ge + 512;                             // 256 i
    int*   bstart = btot + 256;                           // 257 i
    int*   cursor = bstart + 257;                         // 256 i

    hipMemsetAsync(pooled, 0,
                   (size_t)(98304 + 384 + 100000 + 512 + 512 + 256 + 257 + 256) * 4,
                   stream);

    bhist_kernel<<<CBLK, 1024, 0, stream>>>(edge_dst, btot);
    bscan_kernel<<<1, NBKT, 0, stream>>>(btot, bstart, cursor);
    bin_kernel<<<CBLK, 1024, 0, stream>>>(edge_src, edge_dst, cursor, rec);
    fill_kernel<<<NUSED, 1024, 0, stream>>>(rec, bstart, cnt, srcs);

    wprep_kernel<<<18, 256, 0, stream>>>(Ws, whi, wlo);
    embed_kernel<<<(N_NODES * 32 + 255) / 256, 256, 0, stream>>>(node_ids, graph_ids, emb, h, gs, ge);

    const int MLP_BLK = (N_NODES + 127) / 128;   // 782
    for (int l = 0; l < 3; ++l) {
        unsigned short* X = (l % 2 == 0) ? h : xin;
        unsigned short* A = (l % 2 == 0) ? xin : h;
        agg_kernel<<<25000, 256, 0, stream>>>(X, cnt, srcs, eps, l, stats, gamma, beta, A);
        mlp_kernel<<<MLP_BLK, 256, 0, stream>>>(A, whi, wlo, bs, l, stats, graph_ids, pooled, l == 2);
    }

    out_kernel<<<(N_GRAPHS * NUM_CLASSES + 255) / 256, 256, 0, stream>>>(
        pooled, stats, gamma, beta, gs, ge, W_out, b_out, out);
}

// Round 12
// 389.299 us; speedup vs baseline: 1.0347x; 1.0347x over previous
//
#include <hip/hip_runtime.h>

#define N_NODES 100000
#define N_EDGES 1600000
#define N_GRAPHS 512
#define HID 64
#define NUM_CLASSES 100
#define ID_OFFSET 1500
#define BN_EPS 1e-5f
#define CAP 64
#define NBKT 256
#define BSHIFT 9
#define NUSED ((N_NODES + 511) >> 9)   // 196 buckets of 512 nodes
#define BCAP 10240                      // per-bucket record capacity (mean 8192 + 22 sigma)
#define CBLK 98
#define CHUNK 16384

typedef __attribute__((ext_vector_type(8))) short short8;
typedef __attribute__((ext_vector_type(4))) float floatx4;

__device__ __forceinline__ float b2f(unsigned short u) {
    return __builtin_bit_cast(float, ((unsigned)u) << 16);
}
__device__ __forceinline__ unsigned short f2b(float f) {   // RNE
    unsigned x = __builtin_bit_cast(unsigned, f);
    x += 0x7FFFu + ((x >> 16) & 1u);
    return (unsigned short)(x >> 16);
}

// swizzled granule layout: 16-row tiles, 8 granules(16B)/row, granule slot = (row&15)^q
#define XSH(row, qq) ((((((row) >> 4) << 7) + ((qq) << 4) + (((row) & 15) ^ (qq))) * 8))

// ---------------- direct-binning build: ONE pass over edges (replaces bhist+bscan+bin) ----------------
// Fixed-capacity bucket segments rec[b*BCAP ..]; per-block LDS hist -> one global atomic
// per (block,bucket) -> scatter packed records. cursor[b] ends as the bucket total.

__global__ __launch_bounds__(1024) void bin_kernel(const int* __restrict__ src,
                                                   const int* __restrict__ dst,
                                                   int* __restrict__ cursor,
                                                   int* __restrict__ rec) {
    __shared__ int hist[NBKT];
    __shared__ int base_s[NBKT];
    int t = threadIdx.x;
    if (t < NBKT) hist[t] = 0;
    __syncthreads();
    int cb = blockIdx.x * CHUNK;
    int d_[16], s_[16];
#pragma unroll
    for (int k = 0; k < 16; ++k) {
        int i = cb + k * 1024 + t;
        d_[k] = (i < N_EDGES) ? dst[i] : -1;
        s_[k] = (i < N_EDGES) ? src[i] : 0;
        if (d_[k] >= 0) atomicAdd(&hist[((unsigned)d_[k] >> BSHIFT) & (NBKT - 1)], 1);
    }
    __syncthreads();
    if (t < NBKT) base_s[t] = (hist[t] > 0) ? atomicAdd(&cursor[t], hist[t]) : 0;
    __syncthreads();
    if (t < NBKT) hist[t] = 0;     // reuse as running offset
    __syncthreads();
#pragma unroll
    for (int k = 0; k < 16; ++k) {
        if (d_[k] >= 0) {
            unsigned d = (unsigned)d_[k];
            int b = (d >> BSHIFT) & (NBKT - 1);
            int p = atomicAdd(&hist[b], 1);
            int g = base_s[b] + p;
            if ((unsigned)g < BCAP)    // overflow-guard (P ~ 1e-100)
                rec[b * BCAP + g] = ((int)(d & 511) << 17) | (s_[k] & 0x1FFFF);
        }
    }
}

// ---------------- per-bucket CSR fill (reads counts from cursor; fixed segment base) ----------------

__global__ __launch_bounds__(1024) void fill_kernel(const int* __restrict__ rec,
                                                    const int* __restrict__ cursor,
                                                    int* __restrict__ cnt,
                                                    int* __restrict__ srcs) {
    __shared__ int lcnt[512];
    int t = threadIdx.x;
    int b = blockIdx.x;            // 0..NUSED-1
    if (t < 512) lcnt[t] = 0;
    __syncthreads();
    int nb = cursor[b];
    if (nb < 0) nb = 0;
    if (nb > BCAP) nb = BCAP;
    const int* seg = rec + b * BCAP;
    for (int i = t; i < nb; i += 1024) {
        unsigned r = (unsigned)seg[i];
        int dl = (int)((r >> 17) & 511);
        int s = (int)(r & 0x1FFFF);
        int node = (b << BSHIFT) + dl;
        int p = atomicAdd(&lcnt[dl], 1);
        if (p < CAP && node < N_NODES) srcs[(node << 6) + p] = s;
    }
    __syncthreads();
    if (t < 512) {
        int node = (b << BSHIFT) + t;
        if (node < N_NODES) cnt[node] = lcnt[t];
    }
}

// ---------------- W pre-convert + pre-swizzle, hi/lo split ----------------

__global__ void wprep_kernel(const float* __restrict__ Ws, unsigned short* __restrict__ whi,
                             unsigned short* __restrict__ wlo) {
    int G = blockIdx.x * blockDim.x + threadIdx.x;   // granule id, 3*1536
    if (G >= 3 * 1536) return;
    int l = G / 1536, Gp = G % 1536;
    int mm = Gp >> 9, rem = Gp & 511;
    int kq = rem >> 6, n = rem & 63;
    const float* Wp = Ws + l * 12288 + mm * 4096 + (kq * 8) * 64 + n;
    unsigned short uh[8], ul[8];
#pragma unroll
    for (int j = 0; j < 8; ++j) {
        float w = Wp[j * 64];
        unsigned short hi = f2b(w);
        uh[j] = hi;
        ul[j] = f2b(w - b2f(hi));
    }
    size_t off = (size_t)l * 12288 + (mm << 12) + XSH(n, kq);
    *(short8*)&whi[off] = *(short8*)uh;
    *(short8*)&wlo[off] = *(short8*)ul;
}

// ---------------- embedding gather -> bf16 h, fused graph-span detection ----------------

__global__ void embed_kernel(const int* __restrict__ node_ids, const int* __restrict__ gid,
                             const float* __restrict__ emb, unsigned short* __restrict__ h,
                             int* __restrict__ gs, int* __restrict__ ge) {
    int idx = blockIdx.x * blockDim.x + threadIdx.x;
    if (idx < N_NODES * 32) {
        int n = idx >> 5, cp = idx & 31;
        const float2 e = *(const float2*)(emb + (((size_t)(node_ids[n] + ID_OFFSET)) << 6) + cp * 2);
        unsigned v = (unsigned)f2b(e.x) | ((unsigned)f2b(e.y) << 16);
        ((unsigned*)h)[n * 32 + cp] = v;
        if (cp == 0) {   // sorted graph_ids -> span boundaries, no atomics
            int g = gid[n] & (N_GRAPHS - 1);
            if (n == 0 || (gid[n - 1] & (N_GRAPHS - 1)) != g) gs[g] = n;
            if (n == N_NODES - 1 || (gid[n + 1] & (N_GRAPHS - 1)) != g) ge[g] = n + 1;
        }
    }
}

// ---------------- GIN aggregation (half-wave u32, frozen since R10) ----------------

__global__ __launch_bounds__(256) void agg_kernel(const unsigned short* __restrict__ x,
                                                  const int* __restrict__ cnt,
                                                  const int* __restrict__ srcs,
                                                  const float* __restrict__ eps, int l,
                                                  const float* __restrict__ stats,
                                                  const float* __restrict__ gamma,
                                                  const float* __restrict__ beta,
                                                  unsigned short* __restrict__ out) {
    int node = __builtin_amdgcn_readfirstlane((blockIdx.x << 2) + (threadIdx.x >> 6));
    if (node >= N_NODES) return;
    int lane = threadIdx.x & 63;
    int half = lane >> 5;
    int cl = lane & 31;
    const unsigned* __restrict__ xu = (const unsigned*)x;
    int deg = cnt[node];
    int degc = deg < 0 ? 0 : (deg > CAP ? CAP : deg);
    const int* __restrict__ row = srcs + ((size_t)node << 6);
    float scale = 1.0f + eps[l];

    float A0[4] = {0.f, 0.f, 0.f, 0.f};
    float A1[4] = {0.f, 0.f, 0.f, 0.f};
    {
        unsigned u = xu[(size_t)node * 32 + cl];
        if (half == 0) {
            A0[0] = scale * b2f((unsigned short)(u & 0xFFFF));
            A1[0] = scale * b2f((unsigned short)(u >> 16));
        }
    }
    int j = 0;
    for (; j + 16 <= degc; j += 16) {
        unsigned uv[8];
#pragma unroll
        for (int k = 0; k < 8; ++k) {
            int ia = row[j + 2 * k] & 0x1FFFF;
            int ib = row[j + 2 * k + 1] & 0x1FFFF;
            int idx = half ? ib : ia;
            uv[k] = xu[(size_t)idx * 32 + cl];
        }
#pragma unroll
        for (int k = 0; k < 8; ++k) {
            A0[k & 3] += b2f((unsigned short)(uv[k] & 0xFFFF));
            A1[k & 3] += b2f((unsigned short)(uv[k] >> 16));
        }
    }
    for (; j + 8 <= degc; j += 8) {
        unsigned uv[4];
#pragma unroll
        for (int k = 0; k < 4; ++k) {
            int ia = row[j + 2 * k] & 0x1FFFF;
            int ib = row[j + 2 * k + 1] & 0x1FFFF;
            int idx = half ? ib : ia;
            uv[k] = xu[(size_t)idx * 32 + cl];
        }
#pragma unroll
        for (int k = 0; k < 4; ++k) {
            A0[k] += b2f((unsigned short)(uv[k] & 0xFFFF));
            A1[k] += b2f((unsigned short)(uv[k] >> 16));
        }
    }
    for (; j + 2 <= degc; j += 2) {
        int ia = row[j] & 0x1FFFF, ib = row[j + 1] & 0x1FFFF;
        int idx = half ? ib : ia;
        unsigned u = xu[(size_t)idx * 32 + cl];
        A0[1] += b2f((unsigned short)(u & 0xFFFF));
        A1[1] += b2f((unsigned short)(u >> 16));
    }
    if (j < degc && half == 0) {
        unsigned u = xu[(size_t)(row[j] & 0x1FFFF) * 32 + cl];
        A0[2] += b2f((unsigned short)(u & 0xFFFF));
        A1[2] += b2f((unsigned short)(u >> 16));
    }
    float S0 = (A0[0] + A0[1]) + (A0[2] + A0[3]);
    float S1 = (A1[0] + A1[1]) + (A1[2] + A1[3]);
    S0 += __shfl_xor(S0, 32);
    S1 += __shfl_xor(S1, 32);

    if (half == 0) {
        float a0f = 1.0f, a1f = 1.0f, b0f = 0.0f, b1f = 0.0f;
        if (l > 0) {
            int lp = l - 1;
            int c0 = 2 * cl, c1 = 2 * cl + 1;
            float mean0 = stats[lp * 128 + c0] * (1.0f / N_NODES);
            float var0 = stats[lp * 128 + 64 + c0] * (1.0f / N_NODES) - mean0 * mean0;
            float r0 = rsqrtf(var0 + BN_EPS);
            a0f = gamma[lp * 64 + c0] * r0;
            b0f = beta[lp * 64 + c0] - mean0 * a0f;
            float mean1 = stats[lp * 128 + c1] * (1.0f / N_NODES);
            float var1 = stats[lp * 128 + 64 + c1] * (1.0f / N_NODES) - mean1 * mean1;
            float r1 = rsqrtf(var1 + BN_EPS);
            a1f = gamma[lp * 64 + c1] * r1;
            b1f = beta[lp * 64 + c1] - mean1 * a1f;
        }
        float v0 = fmaf(a0f, S0, (scale + (float)degc) * b0f);
        float v1 = fmaf(a1f, S1, (scale + (float)degc) * b1f);
        ((unsigned*)out)[(size_t)node * 32 + cl] =
            (unsigned)f2b(v0) | ((unsigned)f2b(v1) << 16);
    }
}

// ---------------- MFMA MLP (Whi in LDS, Wlo from global; frozen from R11) ----------------

__global__ __launch_bounds__(256) void mlp_kernel(unsigned short* __restrict__ x,
                                                  const unsigned short* __restrict__ whi,
                                                  const unsigned short* __restrict__ wlo,
                                                  const float* __restrict__ bs, int l,
                                                  float* __restrict__ stats,
                                                  const int* __restrict__ graph_ids,
                                                  float* __restrict__ pooled, int last) {
    __shared__ __align__(16) unsigned short xs[128 * 64];    // 16 KB
    __shared__ __align__(16) unsigned short wt[3 * 64 * 64]; // 24 KB (Whi)
    __shared__ int garr[128];
    __shared__ float ssum[256], sqq[256];
    int t = threadIdx.x;
    int nodebase = blockIdx.x * 128;
    int lane = t & 63, w = t >> 6;

    if (lane < 32) {
        int n = nodebase + w * 32 + lane;
        garr[w * 32 + lane] = (n < N_NODES) ? (graph_ids[n] & (N_GRAPHS - 1)) : -1;
    }
#pragma unroll
    for (int i = 0; i < 4; ++i) {
        int g = i * 64 + lane;
        int rl = g >> 3, qr = g & 7;
        int row = w * 32 + rl;
        const int4 v = *(const int4*)(x + (((size_t)(nodebase + row)) << 6) + qr * 8);
        *(int4*)&xs[XSH(row, qr)] = v;
    }
    {
        const unsigned short* wsrc = whi + (size_t)l * 12288;
#pragma unroll
        for (int i = 0; i < 6; ++i) {
            int g = i * 256 + t;
            *(int4*)&wt[g * 8] = *(const int4*)&wsrc[g * 8];
        }
    }
    __syncthreads();

    int m = lane & 15, q = lane >> 4;
    const float* bb = bs + l * 3 * 64;
    const unsigned short* wlol = wlo + (size_t)l * 12288;
    for (int mm = 0; mm < 3; ++mm) {
        floatx4 acc[2][4];
#pragma unroll
        for (int tj = 0; tj < 4; ++tj) {
            float bv = bb[mm * 64 + tj * 16 + m];
#pragma unroll
            for (int ti = 0; ti < 2; ++ti) acc[ti][tj] = (floatx4){bv, bv, bv, bv};
        }
#pragma unroll
        for (int kc = 0; kc < 2; ++kc) {
            short8 a[2], bh[4], bl[4];
#pragma unroll
            for (int ti = 0; ti < 2; ++ti)
                a[ti] = *(const short8*)&xs[XSH(w * 32 + ti * 16 + m, kc * 4 + q)];
#pragma unroll
            for (int tj = 0; tj < 4; ++tj) {
                bh[tj] = *(const short8*)&wt[(mm << 12) + XSH(tj * 16 + m, kc * 4 + q)];
                bl[tj] = *(const short8*)&wlol[(mm << 12) + XSH(tj * 16 + m, kc * 4 + q)];
            }
#pragma unroll
            for (int ti = 0; ti < 2; ++ti)
#pragma unroll
                for (int tj = 0; tj < 4; ++tj) {
                    acc[ti][tj] = __builtin_amdgcn_mfma_f32_16x16x32_bf16(a[ti], bh[tj], acc[ti][tj], 0, 0, 0);
                    acc[ti][tj] = __builtin_amdgcn_mfma_f32_16x16x32_bf16(a[ti], bl[tj], acc[ti][tj], 0, 0, 0);
                }
        }
#pragma unroll
        for (int ti = 0; ti < 2; ++ti)
#pragma unroll
            for (int tj = 0; tj < 4; ++tj) {
                int col = tj * 16 + m;
#pragma unroll
                for (int r = 0; r < 4; ++r) {
                    int row = w * 32 + ti * 16 + q * 4 + r;
                    float v = acc[ti][tj][r];
                    xs[XSH(row, col >> 3) + (col & 7)] = f2b(v > 0.f ? v : 0.f);
                }
            }
    }

    if (!last) {
        unsigned* xo = (unsigned*)x;
#pragma unroll
        for (int it = 0; it < 16; ++it) {
            int row = w * 32 + (lane >> 5) + it * 2;
            int cp = lane & 31;
            int col = cp * 2;
            unsigned val = *(const unsigned*)&xs[XSH(row, col >> 3) + (col & 7)];
            int node = nodebase + row;
            if (node < N_NODES) xo[(size_t)node * 32 + cp] = val;
        }
    }
    {
        int c = lane;
        float s = 0.f, q2 = 0.f, acc2 = 0.f;
        int cur = -1;
        for (int k = 0; k < 32; ++k) {
            int row = w * 32 + k;
            int g = garr[row];
            if (g >= 0) {
                float v = b2f(xs[XSH(row, c >> 3) + (c & 7)]);
                s += v;
                q2 += v * v;
                if (g != cur) {
                    if (cur >= 0) atomicAdd(&pooled[cur * 192 + l * 64 + c], acc2);
                    acc2 = 0.f;
                    cur = g;
                }
                acc2 += v;
            }
        }
        if (cur >= 0) atomicAdd(&pooled[cur * 192 + l * 64 + c], acc2);
        ssum[t] = s;
        sqq[t] = q2;
    }
    __syncthreads();
    if (t < 64) {
        float S = ssum[t] + ssum[t + 64] + ssum[t + 128] + ssum[t + 192];
        float Q = sqq[t] + sqq[t + 64] + sqq[t + 128] + sqq[t + 192];
        atomicAdd(&stats[l * 128 + t], S);
        atomicAdd(&stats[l * 128 + 64 + t], Q);
    }
}

// ---------------- final classifier ----------------

__global__ __launch_bounds__(256) void out_kernel(const float* __restrict__ pooled,
                                                  const float* __restrict__ stats,
                                                  const float* __restrict__ gamma,
                                                  const float* __restrict__ beta,
                                                  const int* __restrict__ gs,
                                                  const int* __restrict__ ge,
                                                  const float* __restrict__ Wo,
                                                  const float* __restrict__ bo,
                                                  float* __restrict__ out) {
    __shared__ float sab[384];
    int t = threadIdx.x;
    if (t < 192) {
        int l2 = t / 64, c = t & 63;
        float mean = stats[l2 * 128 + c] * (1.0f / N_NODES);
        float var = stats[l2 * 128 + 64 + c] * (1.0f / N_NODES) - mean * mean;
        float rstd = rsqrtf(var + BN_EPS);
        float a = gamma[l2 * 64 + c] * rstd;
        sab[l2 * 128 + c] = a;
        sab[l2 * 128 + 64 + c] = beta[l2 * 64 + c] - mean * a;
    }
    __syncthreads();
    int idx = blockIdx.x * blockDim.x + t;
    if (idx < N_GRAPHS * NUM_CLASSES) {
        int g = idx / NUM_CLASSES, k = idx % NUM_CLASSES;
        float cg = (float)(ge[g] - gs[g]);
        float acc = bo[k];
        for (int l2 = 0; l2 < 3; ++l2)
            for (int c = 0; c < 64; ++c) {
                float gf = fmaf(sab[l2 * 128 + c], pooled[g * 192 + l2 * 64 + c],
                                sab[l2 * 128 + 64 + c] * cg);
                acc = fmaf(gf, Wo[(l2 * 64 + c) * NUM_CLASSES + k], acc);
            }
        out[idx] = acc;
    }
}

extern "C" void kernel_launch(void* const* d_in, const int* in_sizes, int n_in,
                              void* d_out, int out_size, void* d_ws, size_t ws_size,
                              hipStream_t stream) {
    const int*   node_ids  = (const int*)d_in[0];
    const int*   edge_src  = (const int*)d_in[1];
    const int*   edge_dst  = (const int*)d_in[2];
    const int*   graph_ids = (const int*)d_in[3];
    const float* emb       = (const float*)d_in[4];
    const float* Ws        = (const float*)d_in[5];
    const float* bs        = (const float*)d_in[6];
    const float* gamma     = (const float*)d_in[7];
    const float* beta      = (const float*)d_in[8];
    const float* eps       = (const float*)d_in[9];
    const float* W_out     = (const float*)d_in[10];
    const float* b_out     = (const float*)d_in[11];
    float* out = (float*)d_out;

    // workspace
    unsigned short* h    = (unsigned short*)d_ws;         // 6,400,000 sh (+8192 slack)
    unsigned short* xin  = h + 6400000 + 8192;            // 6,400,000 sh (+8192 slack)
    unsigned short* whi  = xin + 6400000 + 8192;          // 36,864 sh
    unsigned short* wlo  = whi + 36864;                   // 36,864 sh
    int*   srcs   = (int*)(wlo + 36864);                  // 6,400,000 i (padded CSR)
    int*   rec    = srcs + 6400000;                       // NUSED*BCAP = 2,007,040 i
    float* pooled = (float*)(rec + NUSED * BCAP);         // 98,304 f
    float* stats  = pooled + 98304;                       // 384 f
    int*   cnt    = (int*)(stats + 384);                  // 100,000 i
    int*   gs     = cnt + 100000;                         // 512 i
    int*   ge     = gs + 512;                             // 512 i
    int*   cursor = ge + 512;                             // 256 i (bucket totals)

    // one memset zeroes pooled..cursor (contiguous)
    hipMemsetAsync(pooled, 0,
                   (size_t)(98304 + 384 + 100000 + 512 + 512 + 256) * 4, stream);

    bin_kernel<<<CBLK, 1024, 0, stream>>>(edge_src, edge_dst, cursor, rec);
    fill_kernel<<<NUSED, 1024, 0, stream>>>(rec, cursor, cnt, srcs);

    wprep_kernel<<<18, 256, 0, stream>>>(Ws, whi, wlo);
    embed_kernel<<<(N_NODES * 32 + 255) / 256, 256, 0, stream>>>(node_ids, graph_ids, emb, h, gs, ge);

    const int MLP_BLK = (N_NODES + 127) / 128;   // 782
    for (int l = 0; l < 3; ++l) {
        unsigned short* X = (l % 2 == 0) ? h : xin;
        unsigned short* A = (l % 2 == 0) ? xin : h;
        agg_kernel<<<25000, 256, 0, stream>>>(X, cnt, srcs, eps, l, stats, gamma, beta, A);
        mlp_kernel<<<MLP_BLK, 256, 0, stream>>>(A, whi, wlo, bs, l, stats, graph_ids, pooled, l == 2);
    }

    out_kernel<<<(N_GRAPHS * NUM_CLASSES + 255) / 256, 256, 0, stream>>>(
        pooled, stats, gamma, beta, gs, ge, W_out, b_out, out);
}

// Round 13
// 366.150 us; speedup vs baseline: 1.1001x; 1.0632x over previous
//
#include <hip/hip_runtime.h>

#define N_NODES 100000
#define N_EDGES 1600000
#define N_GRAPHS 512
#define HID 64
#define NUM_CLASSES 100
#define ID_OFFSET 1500
#define BN_EPS 1e-5f
#define CAP 64
#define NBKT 256
#define BSHIFT 9
#define NUSED ((N_NODES + 511) >> 9)   // 196 buckets of 512 nodes
#define BCAP 10240                      // per-bucket record capacity
#define CBLK 98
#define CHUNK 16384
#define WPBLK 5                         // wprep blocks inside prep_kernel
#define EMBBLK ((N_NODES * 32 + 1023) / 1024)   // 3125

typedef __attribute__((ext_vector_type(8))) short short8;
typedef __attribute__((ext_vector_type(4))) float floatx4;

__device__ __forceinline__ float b2f(unsigned short u) {
    return __builtin_bit_cast(float, ((unsigned)u) << 16);
}
__device__ __forceinline__ unsigned short f2b(float f) {   // RNE
    unsigned x = __builtin_bit_cast(unsigned, f);
    x += 0x7FFFu + ((x >> 16) & 1u);
    return (unsigned short)(x >> 16);
}

// swizzled granule layout: 16-row tiles, 8 granules(16B)/row, granule slot = (row&15)^q
#define XSH(row, qq) ((((((row) >> 4) << 7) + ((qq) << 4) + (((row) & 15) ^ (qq))) * 8))

// ---------------- fused prep: direct-binning build + wprep + embed in one launch ----------------
// blocks [0,CBLK): edge binning; [CBLK,CBLK+WPBLK): W hi/lo pre-swizzle;
// [CBLK+WPBLK, ...): embedding gather + graph-span detection. All independent.

__global__ __launch_bounds__(1024) void prep_kernel(const int* __restrict__ src,
                                                    const int* __restrict__ dst,
                                                    int* __restrict__ cursor,
                                                    int* __restrict__ rec,
                                                    const float* __restrict__ Ws,
                                                    unsigned short* __restrict__ whi,
                                                    unsigned short* __restrict__ wlo,
                                                    const int* __restrict__ node_ids,
                                                    const int* __restrict__ gid,
                                                    const float* __restrict__ emb,
                                                    unsigned short* __restrict__ h,
                                                    int* __restrict__ gs,
                                                    int* __restrict__ ge) {
    __shared__ int hist[NBKT];
    __shared__ int base_s[NBKT];
    int t = threadIdx.x;
    int blk = blockIdx.x;

    if (blk < CBLK) {
        // ---- edge binning (one pass) ----
        if (t < NBKT) hist[t] = 0;
        __syncthreads();
        int cb = blk * CHUNK;
        int d_[16], s_[16];
#pragma unroll
        for (int k = 0; k < 16; ++k) {
            int i = cb + k * 1024 + t;
            d_[k] = (i < N_EDGES) ? dst[i] : -1;
            s_[k] = (i < N_EDGES) ? src[i] : 0;
            if (d_[k] >= 0) atomicAdd(&hist[((unsigned)d_[k] >> BSHIFT) & (NBKT - 1)], 1);
        }
        __syncthreads();
        if (t < NBKT) base_s[t] = (hist[t] > 0) ? atomicAdd(&cursor[t], hist[t]) : 0;
        __syncthreads();
        if (t < NBKT) hist[t] = 0;
        __syncthreads();
#pragma unroll
        for (int k = 0; k < 16; ++k) {
            if (d_[k] >= 0) {
                unsigned d = (unsigned)d_[k];
                int b = (d >> BSHIFT) & (NBKT - 1);
                int p = atomicAdd(&hist[b], 1);
                int g = base_s[b] + p;
                if ((unsigned)g < BCAP)
                    rec[b * BCAP + g] = ((int)(d & 511) << 17) | (s_[k] & 0x1FFFF);
            }
        }
    } else if (blk < CBLK + WPBLK) {
        // ---- W pre-convert + pre-swizzle, hi/lo split ----
        int G = (blk - CBLK) * 1024 + t;
        if (G < 3 * 1536) {
            int l = G / 1536, Gp = G % 1536;
            int mm = Gp >> 9, rem = Gp & 511;
            int kq = rem >> 6, n = rem & 63;
            const float* Wp = Ws + l * 12288 + mm * 4096 + (kq * 8) * 64 + n;
            unsigned short uh[8], ul[8];
#pragma unroll
            for (int j = 0; j < 8; ++j) {
                float w = Wp[j * 64];
                unsigned short hi = f2b(w);
                uh[j] = hi;
                ul[j] = f2b(w - b2f(hi));
            }
            size_t off = (size_t)l * 12288 + (mm << 12) + XSH(n, kq);
            *(short8*)&whi[off] = *(short8*)uh;
            *(short8*)&wlo[off] = *(short8*)ul;
        }
    } else {
        // ---- embedding gather (bf16) + sorted-graph span boundaries ----
        int idx = (blk - CBLK - WPBLK) * 1024 + t;
        if (idx < N_NODES * 32) {
            int n = idx >> 5, cp = idx & 31;
            const float2 e = *(const float2*)(emb + (((size_t)(node_ids[n] + ID_OFFSET)) << 6) + cp * 2);
            unsigned v = (unsigned)f2b(e.x) | ((unsigned)f2b(e.y) << 16);
            ((unsigned*)h)[n * 32 + cp] = v;
            if (cp == 0) {
                int g = gid[n] & (N_GRAPHS - 1);
                if (n == 0 || (gid[n - 1] & (N_GRAPHS - 1)) != g) gs[g] = n;
                if (n == N_NODES - 1 || (gid[n + 1] & (N_GRAPHS - 1)) != g) ge[g] = n + 1;
            }
        }
    }
}

// ---------------- per-bucket CSR fill ----------------

__global__ __launch_bounds__(1024) void fill_kernel(const int* __restrict__ rec,
                                                    const int* __restrict__ cursor,
                                                    int* __restrict__ cnt,
                                                    int* __restrict__ srcs) {
    __shared__ int lcnt[512];
    int t = threadIdx.x;
    int b = blockIdx.x;            // 0..NUSED-1
    if (t < 512) lcnt[t] = 0;
    __syncthreads();
    int nb = cursor[b];
    if (nb < 0) nb = 0;
    if (nb > BCAP) nb = BCAP;
    const int* seg = rec + b * BCAP;
    for (int i = t; i < nb; i += 1024) {
        unsigned r = (unsigned)seg[i];
        int dl = (int)((r >> 17) & 511);
        int s = (int)(r & 0x1FFFF);
        int node = (b << BSHIFT) + dl;
        int p = atomicAdd(&lcnt[dl], 1);
        if (p < CAP && node < N_NODES) srcs[(node << 6) + p] = s;
    }
    __syncthreads();
    if (t < 512) {
        int node = (b << BSHIFT) + t;
        if (node < N_NODES) cnt[node] = lcnt[t];
    }
}

// ---------------- GIN aggregation (half-wave u32, frozen since R10) ----------------

__global__ __launch_bounds__(256) void agg_kernel(const unsigned short* __restrict__ x,
                                                  const int* __restrict__ cnt,
                                                  const int* __restrict__ srcs,
                                                  const float* __restrict__ eps, int l,
                                                  const float* __restrict__ stats,
                                                  const float* __restrict__ gamma,
                                                  const float* __restrict__ beta,
                                                  unsigned short* __restrict__ out) {
    int node = __builtin_amdgcn_readfirstlane((blockIdx.x << 2) + (threadIdx.x >> 6));
    if (node >= N_NODES) return;
    int lane = threadIdx.x & 63;
    int half = lane >> 5;
    int cl = lane & 31;
    const unsigned* __restrict__ xu = (const unsigned*)x;
    int deg = cnt[node];
    int degc = deg < 0 ? 0 : (deg > CAP ? CAP : deg);
    const int* __restrict__ row = srcs + ((size_t)node << 6);
    float scale = 1.0f + eps[l];

    float A0[4] = {0.f, 0.f, 0.f, 0.f};
    float A1[4] = {0.f, 0.f, 0.f, 0.f};
    {
        unsigned u = xu[(size_t)node * 32 + cl];
        if (half == 0) {
            A0[0] = scale * b2f((unsigned short)(u & 0xFFFF));
            A1[0] = scale * b2f((unsigned short)(u >> 16));
        }
    }
    int j = 0;
    for (; j + 16 <= degc; j += 16) {
        unsigned uv[8];
#pragma unroll
        for (int k = 0; k < 8; ++k) {
            int ia = row[j + 2 * k] & 0x1FFFF;
            int ib = row[j + 2 * k + 1] & 0x1FFFF;
            int idx = half ? ib : ia;
            uv[k] = xu[(size_t)idx * 32 + cl];
        }
#pragma unroll
        for (int k = 0; k < 8; ++k) {
            A0[k & 3] += b2f((unsigned short)(uv[k] & 0xFFFF));
            A1[k & 3] += b2f((unsigned short)(uv[k] >> 16));
        }
    }
    for (; j + 8 <= degc; j += 8) {
        unsigned uv[4];
#pragma unroll
        for (int k = 0; k < 4; ++k) {
            int ia = row[j + 2 * k] & 0x1FFFF;
            int ib = row[j + 2 * k + 1] & 0x1FFFF;
            int idx = half ? ib : ia;
            uv[k] = xu[(size_t)idx * 32 + cl];
        }
#pragma unroll
        for (int k = 0; k < 4; ++k) {
            A0[k] += b2f((unsigned short)(uv[k] & 0xFFFF));
            A1[k] += b2f((unsigned short)(uv[k] >> 16));
        }
    }
    for (; j + 2 <= degc; j += 2) {
        int ia = row[j] & 0x1FFFF, ib = row[j + 1] & 0x1FFFF;
        int idx = half ? ib : ia;
        unsigned u = xu[(size_t)idx * 32 + cl];
        A0[1] += b2f((unsigned short)(u & 0xFFFF));
        A1[1] += b2f((unsigned short)(u >> 16));
    }
    if (j < degc && half == 0) {
        unsigned u = xu[(size_t)(row[j] & 0x1FFFF) * 32 + cl];
        A0[2] += b2f((unsigned short)(u & 0xFFFF));
        A1[2] += b2f((unsigned short)(u >> 16));
    }
    float S0 = (A0[0] + A0[1]) + (A0[2] + A0[3]);
    float S1 = (A1[0] + A1[1]) + (A1[2] + A1[3]);
    S0 += __shfl_xor(S0, 32);
    S1 += __shfl_xor(S1, 32);

    if (half == 0) {
        float a0f = 1.0f, a1f = 1.0f, b0f = 0.0f, b1f = 0.0f;
        if (l > 0) {
            int lp = l - 1;
            int c0 = 2 * cl, c1 = 2 * cl + 1;
            float mean0 = stats[lp * 128 + c0] * (1.0f / N_NODES);
            float var0 = stats[lp * 128 + 64 + c0] * (1.0f / N_NODES) - mean0 * mean0;
            float r0 = rsqrtf(var0 + BN_EPS);
            a0f = gamma[lp * 64 + c0] * r0;
            b0f = beta[lp * 64 + c0] - mean0 * a0f;
            float mean1 = stats[lp * 128 + c1] * (1.0f / N_NODES);
            float var1 = stats[lp * 128 + 64 + c1] * (1.0f / N_NODES) - mean1 * mean1;
            float r1 = rsqrtf(var1 + BN_EPS);
            a1f = gamma[lp * 64 + c1] * r1;
            b1f = beta[lp * 64 + c1] - mean1 * a1f;
        }
        float v0 = fmaf(a0f, S0, (scale + (float)degc) * b0f);
        float v1 = fmaf(a1f, S1, (scale + (float)degc) * b1f);
        ((unsigned*)out)[(size_t)node * 32 + cl] =
            (unsigned)f2b(v0) | ((unsigned)f2b(v1) << 16);
    }
}

// ---------------- MFMA MLP v4: SPLIT hi/lo accumulator chains ----------------
// R12 diagnosis: interleaved acc=mfma(a,bh,acc);acc=mfma(a,bl,acc) serializes every
// 2nd MFMA behind a ~200-500cyc global wlo load. Split: prefetch bl for this mm
// (loads in flight), run LDS-only hi chain, then lo chain, combine at ReLU.

__global__ __launch_bounds__(256) void mlp_kernel(unsigned short* __restrict__ x,
                                                  const unsigned short* __restrict__ whi,
                                                  const unsigned short* __restrict__ wlo,
                                                  const float* __restrict__ bs, int l,
                                                  float* __restrict__ stats,
                                                  const int* __restrict__ graph_ids,
                                                  float* __restrict__ pooled, int last) {
    __shared__ __align__(16) unsigned short xs[128 * 64];    // 16 KB
    __shared__ __align__(16) unsigned short wt[3 * 64 * 64]; // 24 KB (Whi)
    __shared__ int garr[128];
    __shared__ float ssum[256], sqq[256];
    int t = threadIdx.x;
    int nodebase = blockIdx.x * 128;
    int lane = t & 63, w = t >> 6;

    if (lane < 32) {
        int n = nodebase + w * 32 + lane;
        garr[w * 32 + lane] = (n < N_NODES) ? (graph_ids[n] & (N_GRAPHS - 1)) : -1;
    }
#pragma unroll
    for (int i = 0; i < 4; ++i) {
        int g = i * 64 + lane;
        int rl = g >> 3, qr = g & 7;
        int row = w * 32 + rl;
        const int4 v = *(const int4*)(x + (((size_t)(nodebase + row)) << 6) + qr * 8);
        *(int4*)&xs[XSH(row, qr)] = v;
    }
    {
        const unsigned short* wsrc = whi + (size_t)l * 12288;
#pragma unroll
        for (int i = 0; i < 6; ++i) {
            int g = i * 256 + t;
            *(int4*)&wt[g * 8] = *(const int4*)&wsrc[g * 8];
        }
    }
    __syncthreads();

    int m = lane & 15, q = lane >> 4;
    const float* bb = bs + l * 3 * 64;
    const unsigned short* wlol = wlo + (size_t)l * 12288;
    for (int mm = 0; mm < 3; ++mm) {
        // prefetch lo fragments for this mm (global loads go in flight now)
        short8 bl[2][4];
#pragma unroll
        for (int kc = 0; kc < 2; ++kc)
#pragma unroll
            for (int tj = 0; tj < 4; ++tj)
                bl[kc][tj] = *(const short8*)&wlol[(mm << 12) + XSH(tj * 16 + m, kc * 4 + q)];
        // A fragments (LDS, own rows)
        short8 a[2][2];
#pragma unroll
        for (int kc = 0; kc < 2; ++kc)
#pragma unroll
            for (int ti = 0; ti < 2; ++ti)
                a[kc][ti] = *(const short8*)&xs[XSH(w * 32 + ti * 16 + m, kc * 4 + q)];

        floatx4 acch[2][4], accl[2][4];
#pragma unroll
        for (int tj = 0; tj < 4; ++tj) {
            float bv = bb[mm * 64 + tj * 16 + m];
#pragma unroll
            for (int ti = 0; ti < 2; ++ti) {
                acch[ti][tj] = (floatx4){bv, bv, bv, bv};
                accl[ti][tj] = (floatx4){0.f, 0.f, 0.f, 0.f};
            }
        }
        // hi chain: LDS-only dependencies, 16 back-to-back MFMAs
#pragma unroll
        for (int kc = 0; kc < 2; ++kc) {
            short8 bh[4];
#pragma unroll
            for (int tj = 0; tj < 4; ++tj)
                bh[tj] = *(const short8*)&wt[(mm << 12) + XSH(tj * 16 + m, kc * 4 + q)];
#pragma unroll
            for (int ti = 0; ti < 2; ++ti)
#pragma unroll
                for (int tj = 0; tj < 4; ++tj)
                    acch[ti][tj] = __builtin_amdgcn_mfma_f32_16x16x32_bf16(a[kc][ti], bh[tj], acch[ti][tj], 0, 0, 0);
        }
        // lo chain: consumes the prefetched (now-arrived) bl fragments
#pragma unroll
        for (int kc = 0; kc < 2; ++kc)
#pragma unroll
            for (int ti = 0; ti < 2; ++ti)
#pragma unroll
                for (int tj = 0; tj < 4; ++tj)
                    accl[ti][tj] = __builtin_amdgcn_mfma_f32_16x16x32_bf16(a[kc][ti], bl[kc][tj], accl[ti][tj], 0, 0, 0);
        // combine + ReLU + write-back (wave-local rows)
#pragma unroll
        for (int ti = 0; ti < 2; ++ti)
#pragma unroll
            for (int tj = 0; tj < 4; ++tj) {
                int col = tj * 16 + m;
#pragma unroll
                for (int r = 0; r < 4; ++r) {
                    int row = w * 32 + ti * 16 + q * 4 + r;
                    float v = acch[ti][tj][r] + accl[ti][tj][r];
                    xs[XSH(row, col >> 3) + (col & 7)] = f2b(v > 0.f ? v : 0.f);
                }
            }
    }

    if (!last) {
        unsigned* xo = (unsigned*)x;
#pragma unroll
        for (int it = 0; it < 16; ++it) {
            int row = w * 32 + (lane >> 5) + it * 2;
            int cp = lane & 31;
            int col = cp * 2;
            unsigned val = *(const unsigned*)&xs[XSH(row, col >> 3) + (col & 7)];
            int node = nodebase + row;
            if (node < N_NODES) xo[(size_t)node * 32 + cp] = val;
        }
    }
    {
        int c = lane;
        float s = 0.f, q2 = 0.f, acc2 = 0.f;
        int cur = -1;
        for (int k = 0; k < 32; ++k) {
            int row = w * 32 + k;
            int g = garr[row];
            if (g >= 0) {
                float v = b2f(xs[XSH(row, c >> 3) + (c & 7)]);
                s += v;
                q2 += v * v;
                if (g != cur) {
                    if (cur >= 0) atomicAdd(&pooled[cur * 192 + l * 64 + c], acc2);
                    acc2 = 0.f;
                    cur = g;
                }
                acc2 += v;
            }
        }
        if (cur >= 0) atomicAdd(&pooled[cur * 192 + l * 64 + c], acc2);
        ssum[t] = s;
        sqq[t] = q2;
    }
    __syncthreads();
    if (t < 64) {
        float S = ssum[t] + ssum[t + 64] + ssum[t + 128] + ssum[t + 192];
        float Q = sqq[t] + sqq[t + 64] + sqq[t + 128] + sqq[t + 192];
        atomicAdd(&stats[l * 128 + t], S);
        atomicAdd(&stats[l * 128 + 64 + t], Q);
    }
}

// ---------------- final classifier ----------------

__global__ __launch_bounds__(256) void out_kernel(const float* __restrict__ pooled,
                                                  const float* __restrict__ stats,
                                                  const float* __restrict__ gamma,
                                                  const float* __restrict__ beta,
                                                  const int* __restrict__ gs,
                                                  const int* __restrict__ ge,
                                                  const float* __restrict__ Wo,
                                                  const float* __restrict__ bo,
                                                  float* __restrict__ out) {
    __shared__ float sab[384];
    int t = threadIdx.x;
    if (t < 192) {
        int l2 = t / 64, c = t & 63;
        float mean = stats[l2 * 128 + c] * (1.0f / N_NODES);
        float var = stats[l2 * 128 + 64 + c] * (1.0f / N_NODES) - mean * mean;
        float rstd = rsqrtf(var + BN_EPS);
        float a = gamma[l2 * 64 + c] * rstd;
        sab[l2 * 128 + c] = a;
        sab[l2 * 128 + 64 + c] = beta[l2 * 64 + c] - mean * a;
    }
    __syncthreads();
    int idx = blockIdx.x * blockDim.x + t;
    if (idx < N_GRAPHS * NUM_CLASSES) {
        int g = idx / NUM_CLASSES, k = idx % NUM_CLASSES;
        float cg = (float)(ge[g] - gs[g]);
        float acc = bo[k];
        for (int l2 = 0; l2 < 3; ++l2)
            for (int c = 0; c < 64; ++c) {
                float gf = fmaf(sab[l2 * 128 + c], pooled[g * 192 + l2 * 64 + c],
                                sab[l2 * 128 + 64 + c] * cg);
                acc = fmaf(gf, Wo[(l2 * 64 + c) * NUM_CLASSES + k], acc);
            }
        out[idx] = acc;
    }
}

extern "C" void kernel_launch(void* const* d_in, const int* in_sizes, int n_in,
                              void* d_out, int out_size, void* d_ws, size_t ws_size,
                              hipStream_t stream) {
    const int*   node_ids  = (const int*)d_in[0];
    const int*   edge_src  = (const int*)d_in[1];
    const int*   edge_dst  = (const int*)d_in[2];
    const int*   graph_ids = (const int*)d_in[3];
    const float* emb       = (const float*)d_in[4];
    const float* Ws        = (const float*)d_in[5];
    const float* bs        = (const float*)d_in[6];
    const float* gamma     = (const float*)d_in[7];
    const float* beta      = (const float*)d_in[8];
    const float* eps       = (const float*)d_in[9];
    const float* W_out     = (const float*)d_in[10];
    const float* b_out     = (const float*)d_in[11];
    float* out = (float*)d_out;

    // workspace
    unsigned short* h    = (unsigned short*)d_ws;         // 6,400,000 sh (+8192 slack)
    unsigned short* xin  = h + 6400000 + 8192;            // 6,400,000 sh (+8192 slack)
    unsigned short* whi  = xin + 6400000 + 8192;          // 36,864 sh
    unsigned short* wlo  = whi + 36864;                   // 36,864 sh
    int*   srcs   = (int*)(wlo + 36864);                  // 6,400,000 i (padded CSR)
    int*   rec    = srcs + 6400000;                       // NUSED*BCAP i
    float* pooled = (float*)(rec + NUSED * BCAP);         // 98,304 f
    float* stats  = pooled + 98304;                       // 384 f
    int*   cnt    = (int*)(stats + 384);                  // 100,000 i
    int*   gs     = cnt + 100000;                         // 512 i
    int*   ge     = gs + 512;                             // 512 i
    int*   cursor = ge + 512;                             // 256 i (bucket totals)

    hipMemsetAsync(pooled, 0,
                   (size_t)(98304 + 384 + 100000 + 512 + 512 + 256) * 4, stream);

    prep_kernel<<<CBLK + WPBLK + EMBBLK, 1024, 0, stream>>>(
        edge_src, edge_dst, cursor, rec, Ws, whi, wlo,
        node_ids, graph_ids, emb, h, gs, ge);
    fill_kernel<<<NUSED, 1024, 0, stream>>>(rec, cursor, cnt, srcs);

    const int MLP_BLK = (N_NODES + 127) / 128;   // 782
    for (int l = 0; l < 3; ++l) {
        unsigned short* X = (l % 2 == 0) ? h : xin;
        unsigned short* A = (l % 2 == 0) ? xin : h;
        agg_kernel<<<25000, 256, 0, stream>>>(X, cnt, srcs, eps, l, stats, gamma, beta, A);
        mlp_kernel<<<MLP_BLK, 256, 0, stream>>>(A, whi, wlo, bs, l, stats, graph_ids, pooled, l == 2);
    }

    out_kernel<<<(N_GRAPHS * NUM_CLASSES + 255) / 256, 256, 0, stream>>>(
        pooled, stats, gamma, beta, gs, ge, W_out, b_out, out);
}